// Round 3
// baseline (1287.689 us; speedup 1.0000x reference)
//
#include <hip/hip_runtime.h>
#include <stdint.h>

// ParallelFcWithAttention: B=16384, F=10, D=512, H=8, DH=64
// R3: barrier-free K-loops via wave-private B staging.
//  kern_attn: 4 batch/wg, 2 blk/CU. Wave w owns C-cols [48w,48w+48): stages its own
//   K=32 B-slabs (dbuf 2x3072, K-major layout -> conflict-free ds_read_b128),
//   zero K-loop barriers; R1's scalar attention (5 cheap syncthreads/head).
//  kern_out: B (Wo) wave-private dbuf, A-frags direct-from-global (2-deep reg prefetch),
//   zero K-loop barriers.

typedef __bf16 bf16;
typedef __bf16 bf16x8 __attribute__((ext_vector_type(8)));
typedef float f32x4 __attribute__((ext_vector_type(4)));

#define EPS 1e-5f

static constexpr size_t O_ELEMS   = (size_t)16384 * 10 * 512;
static constexpr size_t O_BYTES   = O_ELEMS * 2;                // 167,772,160
static constexpr size_t WQKV_BYTES = (size_t)8 * 192 * 512 * 2;

__device__ __forceinline__ void async_copy16(void* lds, const void* g) {
  __builtin_amdgcn_global_load_lds(
      (const __attribute__((address_space(1))) uint32_t*)g,
      (__attribute__((address_space(3))) uint32_t*)lds, 16, 0, 0);
}
// gfx9 waitcnt: vmcnt[3:0]|[15:14], expcnt[6:4], lgkmcnt[11:8]; 0x0F70 = vmcnt-only base
#define WAIT_VM(n) __builtin_amdgcn_s_waitcnt(0x0F70 | (n))

// ---------------- pack weights to bf16 ----------------
__global__ __launch_bounds__(256) void pack_weights(
    const float* __restrict__ Wq, const float* __restrict__ Wk,
    const float* __restrict__ Wv, const float* __restrict__ Wo,
    bf16* __restrict__ wqkv, bf16* __restrict__ wob) {
  int idx = blockIdx.x * 256 + threadIdx.x;
#pragma unroll
  for (int u = 0; u < 4; ++u) {
    int i = idx + u * 262144;
    if (i < 786432) {
      int pr = i >> 9, k = i & 511;
      int h = pr / 192, w = pr - h * 192;
      int t = w >> 6, r = w & 63;
      const float* src = (t == 0) ? Wq : ((t == 1) ? Wk : Wv);
      wqkv[i] = (bf16)src[(h * 64 + r) * 512 + k];
    } else {
      int j = i - 786432;
      wob[j] = (bf16)Wo[j];
    }
  }
}

// ---------------- fused P + QKV + attention ----------------
// LDS: sA [8 k-slabs][48 rows][128 B] XOR-swizzled (shared, read-only after 1 barrier)
//      sB 24576: GEMM phase: wave w private dbuf at w*6144 (2 x 3072, K-major:
//        slab = [3 nt-copies][4 kchunks x 256][16 rows x 16B])
//        attn phase union: qkv[48][200] bf16 @0 | sc[4][10][12] f32 @19200
__global__ __launch_bounds__(256, 2) void kern_attn(
    const float* __restrict__ x, const float* __restrict__ Wf,
    const float* __restrict__ bfv, const bf16* __restrict__ wqkv,
    const float* __restrict__ bq, const float* __restrict__ bk,
    const float* __restrict__ bv, bf16* __restrict__ O) {
  __shared__ __align__(16) char sA[49152];
  __shared__ __align__(16) char sB[24576];
  bf16* qkv = (bf16*)sB;
  float* sc = (float*)(sB + 19200);

  const int tid = threadIdx.x;
  const int wave = tid >> 6, lane = tid & 63;
  const int lm = lane & 15, lg = lane >> 4;
  const int b0 = blockIdx.x * 4;

  char* myB = sB + wave * 6144;
  const int srow = lane & 15;        // staged row within 16-row copy
  const int schunk = lane >> 4;      // k-octet 0..3
  // source base for wave's B rows: global row = 48*wave + 16*c + srow, k = s*32 + schunk*8
  const bf16* wbase = wqkv + (size_t)(48 * wave + srow) * 512 + schunk * 8;

  // prologue: head 0 slabs 0,1 (before P-gen barrier -- sB untouched by P-gen)
#pragma unroll
  for (int c = 0; c < 3; ++c) async_copy16(myB + c * 1024, wbase + (size_t)c * 8192);
#pragma unroll
  for (int c = 0; c < 3; ++c) async_copy16(myB + 3072 + c * 1024, wbase + (size_t)c * 8192 + 32);

  // ---- P = relu(x*Wf + bf) into sA (rows >=40 zeroed), chunk' = chunk ^ (row&7) ----
#pragma unroll
  for (int it = 0; it < 12; ++it) {
    int c = tid + it * 256;
    int s = c / 384, rem = c - s * 384;
    int r = rem >> 3, kcp = rem & 7;
    int kc = kcp ^ (r & 7);
    int k = s * 64 + kc * 8;
    bf16x8 pv;
    if (r < 40) {
      int bl = r / 10, f = r - bl * 10;
      float xv = x[(b0 + bl) * 10 + f];
      const float* wf = Wf + f * 512 + k;
      const float* bp = bfv + f * 512 + k;
#pragma unroll
      for (int j = 0; j < 8; ++j) pv[j] = (bf16)fmaxf(xv * wf[j] + bp[j], 0.f);
    } else {
#pragma unroll
      for (int j = 0; j < 8; ++j) pv[j] = (bf16)0.f;
    }
    *(bf16x8*)(sA + s * 6144 + r * 128 + kcp * 16) = pv;
  }
  __syncthreads();

  for (int h = 0; h < 8; ++h) {
    f32x4 acc[3][3];
#pragma unroll
    for (int i = 0; i < 3; ++i)
#pragma unroll
      for (int j = 0; j < 3; ++j) { f32x4 z = {0.f, 0.f, 0.f, 0.f}; acc[i][j] = z; }

    // ---- barrier-free K-loop: 16 steps of K=32, wave-private B dbuf ----
#pragma unroll
    for (int s = 0; s < 16; ++s) {
      if (s < 15) WAIT_VM(3); else WAIT_VM(0);
      const char* buf = myB + (s & 1) * 3072;
      const char* sAs = sA + (s >> 1) * 6144;
      const int kc = (s & 1) * 4 + lg;
      bf16x8 af[3], bfr[3];
#pragma unroll
      for (int mt = 0; mt < 3; ++mt) {
        int m = mt * 16 + lm;
        af[mt] = *(const bf16x8*)(sAs + m * 128 + ((kc ^ (m & 7)) << 4));
      }
#pragma unroll
      for (int nt = 0; nt < 3; ++nt)
        bfr[nt] = *(const bf16x8*)(buf + nt * 1024 + lg * 256 + lm * 16);
#pragma unroll
      for (int mt = 0; mt < 3; ++mt)
#pragma unroll
        for (int nt = 0; nt < 3; ++nt)
          acc[mt][nt] = __builtin_amdgcn_mfma_f32_16x16x32_bf16(af[mt], bfr[nt], acc[mt][nt], 0, 0, 0);
      if (s < 14) {
#pragma unroll
        for (int c = 0; c < 3; ++c)
          async_copy16(myB + (s & 1) * 3072 + c * 1024,
                       wbase + (size_t)h * 98304 + (size_t)c * 8192 + (s + 2) * 32);
      }
    }
    __syncthreads();   // all waves done K-loop; sB union free for attn

    // ---- spill q/k/v (+bias) to shared qkv ----
#pragma unroll
    for (int nt = 0; nt < 3; ++nt) {
      int col = wave * 48 + nt * 16 + lm;
      float bias;
      if (col < 64) bias = bq[h * 64 + col];
      else if (col < 128) bias = bk[h * 64 + col - 64];
      else bias = bv[h * 64 + col - 128];
#pragma unroll
      for (int mt = 0; mt < 3; ++mt)
#pragma unroll
        for (int r = 0; r < 4; ++r) {
          int row = mt * 16 + lg * 4 + r;
          if (row < 40) qkv[row * 200 + col] = (bf16)(acc[mt][nt][r] + bias);
        }
    }
    __syncthreads();

    // ---- scores: one wave per batch elem ----
    {
      int b = wave;
#pragma unroll
      for (int pp = 0; pp < 2; ++pp) {
        int p = lane + pp * 64;
        if (p < 100) {
          int i = p / 10, j = p - i * 10;
          const bf16x8* qr = (const bf16x8*)(qkv + (b * 10 + i) * 200);
          const bf16x8* kr = (const bf16x8*)(qkv + (b * 10 + j) * 200 + 64);
          float d = 0.f;
#pragma unroll
          for (int c8 = 0; c8 < 8; ++c8) {
            bf16x8 qv = qr[c8], kv = kr[c8];
#pragma unroll
            for (int e = 0; e < 8; ++e) d += (float)qv[e] * (float)kv[e];
          }
          sc[(b * 10 + i) * 12 + j] = d * 0.125f;
        }
      }
    }
    __syncthreads();

    // ---- softmax, one thread per (b,i) ----
    if (tid < 40) {
      float* row = sc + tid * 12;
      float m = row[0];
#pragma unroll
      for (int j = 1; j < 10; ++j) m = fmaxf(m, row[j]);
      float e[10], sum = 0.f;
#pragma unroll
      for (int j = 0; j < 10; ++j) { e[j] = __expf(row[j] - m); sum += e[j]; }
      float inv = 1.f / sum;
#pragma unroll
      for (int j = 0; j < 10; ++j) row[j] = e[j] * inv;
    }
    __syncthreads();

    // ---- o = attn @ v -> O bf16 ----
#pragma unroll
    for (int u = 0; u < 10; ++u) {
      int id = tid + u * 256;
      int b = id / 640, rem2 = id - b * 640;
      int i = rem2 >> 6, d = rem2 & 63;
      const float* ar = sc + (b * 10 + i) * 12;
      float o = 0.f;
#pragma unroll
      for (int j = 0; j < 10; ++j)
        o += ar[j] * (float)qkv[(b * 10 + j) * 200 + 128 + d];
      O[((size_t)(b0 + b) * 10 + i) * 512 + h * 64 + d] = (bf16)o;
    }
    __syncthreads();   // qkv/sc dead; safe to overwrite sB with next head's slabs

    if (h < 7) {
#pragma unroll
      for (int c = 0; c < 3; ++c)
        async_copy16(myB + c * 1024, wbase + (size_t)(h + 1) * 98304 + (size_t)c * 8192);
#pragma unroll
      for (int c = 0; c < 3; ++c)
        async_copy16(myB + 3072 + c * 1024,
                     wbase + (size_t)(h + 1) * 98304 + (size_t)c * 8192 + 32);
    }
  }
}

// ---------------- O @ Wo.T + bo -> LayerNorm -> sum over F ----------------
// Wave w owns C-cols [128w,128w+128): wave-private Wo dbuf (2x8192, K-major).
// A-frags direct from global (O rows are wg-private, LLC-resident), 2-deep reg prefetch.
// LDS: B2 65536 | partial 1536 | stats 384; epilogue lnb[48][520] overlays B2.
__global__ __launch_bounds__(256, 2) void kern_out(
    const bf16* __restrict__ Oin, const bf16* __restrict__ wob,
    const float* __restrict__ bo, const float* __restrict__ gamma,
    const float* __restrict__ beta, float* __restrict__ out) {
  __shared__ __align__(16) char smem[67456];
  char* B2 = smem;
  float* partial = (float*)(smem + 65536);      // [48][4][2]
  float* stats = (float*)(smem + 65536 + 1536); // [48][2]
  bf16* lnb = (bf16*)smem;                      // epilogue overlay [48][520]

  const int tid = threadIdx.x;
  const int wave = tid >> 6, lane = tid & 63;
  const int lm = lane & 15, lg = lane >> 4;
  const int m0 = blockIdx.x * 40;
  const int srow = lane & 15, schunk = lane >> 4;

  char* myB = B2 + wave * 16384;
  const bf16* wb = wob + (size_t)(128 * wave + srow) * 512 + schunk * 8;

  const bf16* arow[3];
#pragma unroll
  for (int mt = 0; mt < 3; ++mt) {
    int r = mt * 16 + lm; if (r > 39) r = 39;
    arow[mt] = Oin + (size_t)(m0 + r) * 512 + lg * 8;
  }

  f32x4 acc[3][8];
#pragma unroll
  for (int i = 0; i < 3; ++i)
#pragma unroll
    for (int j = 0; j < 8; ++j) { f32x4 z = {0.f, 0.f, 0.f, 0.f}; acc[i][j] = z; }

  // prologue: B slabs 0,1 (8 copies each), A prefetch s=0,1
#pragma unroll
  for (int c = 0; c < 8; ++c)
    async_copy16(myB + c * 1024, wb + (size_t)c * 8192);
#pragma unroll
  for (int c = 0; c < 8; ++c)
    async_copy16(myB + 8192 + c * 1024, wb + (size_t)c * 8192 + 32);
  bf16x8 afp[2][3];
#pragma unroll
  for (int mt = 0; mt < 3; ++mt) afp[0][mt] = *(const bf16x8*)(arow[mt]);
#pragma unroll
  for (int mt = 0; mt < 3; ++mt) afp[1][mt] = *(const bf16x8*)(arow[mt] + 32);

#pragma unroll
  for (int s = 0; s < 16; ++s) {
    if (s == 0) WAIT_VM(3);
    else if (s < 15) WAIT_VM(11);
    else WAIT_VM(0);
    const char* buf = myB + (s & 1) * 8192;
    bf16x8 bfr[8];
#pragma unroll
    for (int nt = 0; nt < 8; ++nt)
      bfr[nt] = *(const bf16x8*)(buf + nt * 1024 + lg * 256 + lm * 16);
#pragma unroll
    for (int mt = 0; mt < 3; ++mt)
#pragma unroll
      for (int nt = 0; nt < 8; ++nt)
        acc[mt][nt] = __builtin_amdgcn_mfma_f32_16x16x32_bf16(afp[s & 1][mt], bfr[nt], acc[mt][nt], 0, 0, 0);
    if (s < 14) {
#pragma unroll
      for (int mt = 0; mt < 3; ++mt)
        afp[s & 1][mt] = *(const bf16x8*)(arow[mt] + (s + 2) * 32);
#pragma unroll
      for (int c = 0; c < 8; ++c)
        async_copy16(myB + (s & 1) * 8192 + c * 1024, wb + (size_t)c * 8192 + (s + 2) * 32);
    }
  }

  // + bias
#pragma unroll
  for (int nt = 0; nt < 8; ++nt) {
    int col = wave * 128 + nt * 16 + lm;
    float bb = bo[col];
#pragma unroll
    for (int mt = 0; mt < 3; ++mt)
#pragma unroll
      for (int r = 0; r < 4; ++r) acc[mt][nt][r] += bb;
  }

  // per-row mean/var partials
#pragma unroll
  for (int mt = 0; mt < 3; ++mt)
#pragma unroll
    for (int r = 0; r < 4; ++r) {
      float s1 = 0.f, s2 = 0.f;
#pragma unroll
      for (int nt = 0; nt < 8; ++nt) { float v = acc[mt][nt][r]; s1 += v; s2 += v * v; }
#pragma unroll
      for (int off = 1; off < 16; off <<= 1) {
        s1 += __shfl_xor(s1, off);
        s2 += __shfl_xor(s2, off);
      }
      if (lm == 0) {
        int row = mt * 16 + lg * 4 + r;
        partial[row * 8 + wave * 2 + 0] = s1;
        partial[row * 8 + wave * 2 + 1] = s2;
      }
    }
  __syncthreads();   // gates: all waves past K-loop; lnb overlay of B2 is safe after this
  if (tid < 48) {
    float s1 = partial[tid * 8 + 0] + partial[tid * 8 + 2] + partial[tid * 8 + 4] + partial[tid * 8 + 6];
    float s2 = partial[tid * 8 + 1] + partial[tid * 8 + 3] + partial[tid * 8 + 5] + partial[tid * 8 + 7];
    float mu = s1 * (1.f / 512.f);
    float var = s2 * (1.f / 512.f) - mu * mu;
    stats[tid * 2 + 0] = mu;
    stats[tid * 2 + 1] = rsqrtf(var + EPS);
  }
  __syncthreads();
  // normalized values -> lnb bf16 (overlays dead B2)
#pragma unroll
  for (int mt = 0; mt < 3; ++mt)
#pragma unroll
    for (int r = 0; r < 4; ++r) {
      int row = mt * 16 + lg * 4 + r;
      float mu = stats[row * 2 + 0], rr = stats[row * 2 + 1];
#pragma unroll
      for (int nt = 0; nt < 8; ++nt) {
        int col = wave * 128 + nt * 16 + lm;
        lnb[row * 520 + col] = (bf16)((acc[mt][nt][r] - mu) * rr);
      }
    }
  __syncthreads();
  // out[b,n] = gamma[n]*sum_f lnv + 10*beta[n]
#pragma unroll
  for (int u = 0; u < 8; ++u) {
    int id = tid + u * 256;
    int b = id >> 9, n = id & 511;
    float ssum = 0.f;
#pragma unroll
    for (int f = 0; f < 10; ++f) ssum += (float)lnb[(b * 10 + f) * 520 + n];
    out[(size_t)(blockIdx.x * 4 + b) * 512 + n] = gamma[n] * ssum + 10.f * beta[n];
  }
}

extern "C" void kernel_launch(void* const* d_in, const int* in_sizes, int n_in,
                              void* d_out, int out_size, void* d_ws, size_t ws_size,
                              hipStream_t stream) {
  const float* x     = (const float*)d_in[0];
  const float* Wf    = (const float*)d_in[1];
  const float* bfv   = (const float*)d_in[2];
  const float* Wq    = (const float*)d_in[3];
  const float* Wk    = (const float*)d_in[4];
  const float* Wv    = (const float*)d_in[5];
  const float* bq    = (const float*)d_in[6];
  const float* bk    = (const float*)d_in[7];
  const float* bv    = (const float*)d_in[8];
  const float* Wo    = (const float*)d_in[9];
  const float* bo    = (const float*)d_in[10];
  const float* gamma = (const float*)d_in[11];
  const float* beta  = (const float*)d_in[12];
  float* out = (float*)d_out;

  char* ws = (char*)d_ws;
  bf16* O    = (bf16*)ws;
  bf16* wqkv = (bf16*)(ws + O_BYTES);
  bf16* wob  = (bf16*)(ws + O_BYTES + WQKV_BYTES);

  pack_weights<<<1024, 256, 0, stream>>>(Wq, Wk, Wv, Wo, wqkv, wob);
  kern_attn<<<4096, 256, 0, stream>>>(x, Wf, bfv, wqkv, bq, bk, bv, O);
  kern_out<<<4096, 256, 0, stream>>>(O, wob, bo, gamma, beta, out);
}

// Round 5
// 1249.772 us; speedup vs baseline: 1.0303x; 1.0303x over previous
//
#include <hip/hip_runtime.h>
#include <stdint.h>

// ParallelFcWithAttention: B=16384, F=10, D=512, H=8, DH=64
// R5 = R4 with compile fix: s_waitcnt needs a literal-constant arg -> templated
//  wait_vm<N>() dispatched by constant-foldable branches on the unrolled loop var.
// R4 design: GEMMs stream B (and A in kern_out) DIRECTLY to registers (MFMA frag =
//  16B/lane global_load_dwordx4, 16 rows x 64B segments, L2-resident weights).
//  No LDS staging for B, no K-loop barriers, rotating register buffers with
//  explicit vmcnt waits (consume-then-refill).
// MFMA frag (m89-verified): A/B lane holds [row=lane&15][k=(lane>>4)*8+j];
//  C/D: row=(lane>>4)*4+r, col=lane&15.

typedef __bf16 bf16;
typedef __bf16 bf16x8 __attribute__((ext_vector_type(8)));
typedef float f32x4 __attribute__((ext_vector_type(4)));

#define EPS 1e-5f

static constexpr size_t O_ELEMS   = (size_t)16384 * 10 * 512;
static constexpr size_t O_BYTES   = O_ELEMS * 2;                // 167,772,160
static constexpr size_t WQKV_BYTES = (size_t)8 * 192 * 512 * 2;

// gfx9 waitcnt: vmcnt bits [3:0]+[15:14], expcnt [6:4], lgkmcnt [11:8]
template <int N>
__device__ __forceinline__ void wait_vm() {
  __builtin_amdgcn_s_waitcnt(0x0F70 | (N & 15) | ((N >> 4) << 14));
}

// ---------------- pack weights to bf16 ----------------
__global__ __launch_bounds__(256) void pack_weights(
    const float* __restrict__ Wq, const float* __restrict__ Wk,
    const float* __restrict__ Wv, const float* __restrict__ Wo,
    bf16* __restrict__ wqkv, bf16* __restrict__ wob) {
  int idx = blockIdx.x * 256 + threadIdx.x;
#pragma unroll
  for (int u = 0; u < 4; ++u) {
    int i = idx + u * 262144;
    if (i < 786432) {
      int pr = i >> 9, k = i & 511;
      int h = pr / 192, w = pr - h * 192;
      int t = w >> 6, r = w & 63;
      const float* src = (t == 0) ? Wq : ((t == 1) ? Wk : Wv);
      wqkv[i] = (bf16)src[(h * 64 + r) * 512 + k];
    } else {
      int j = i - 786432;
      wob[j] = (bf16)Wo[j];
    }
  }
}

// ---------------- fused P + QKV + attention ----------------
// LDS: sA = P [8 slabs(K=64)][48 rows][128B] XOR-swizzled; sQ = qkv[48][200]bf16 + sc[4][10][12]f32.
// Wave w owns QKV cols [48w,48w+48). B-frags direct global->reg, 4-slot rotation.
__global__ __launch_bounds__(256, 2) void kern_attn(
    const float* __restrict__ x, const float* __restrict__ Wf,
    const float* __restrict__ bfv, const bf16* __restrict__ wqkv,
    const float* __restrict__ bq, const float* __restrict__ bk,
    const float* __restrict__ bv, bf16* __restrict__ O) {
  __shared__ __align__(16) char sA[49152];
  __shared__ __align__(16) char sQ[21120];
  bf16* qkv = (bf16*)sQ;                 // [48][200]: q 0-63 | k 64-127 | v 128-191
  float* sc = (float*)(sQ + 19200);      // [4][10][12]

  const int tid = threadIdx.x;
  const int wave = tid >> 6, lane = tid & 63;
  const int lm = lane & 15, lg = lane >> 4;
  const int b0 = blockIdx.x * 4;

  // B-frag source rows (per-head offset added in-loop)
  const bf16* wrow[3];
#pragma unroll
  for (int nt = 0; nt < 3; ++nt)
    wrow[nt] = wqkv + (size_t)(wave * 48 + nt * 16 + lm) * 512 + lg * 8;

  // prologue: head 0, chunk-sets 0..3 (12 loads in flight during P-gen)
  bf16x8 bpre[4][3];
#pragma unroll
  for (int p = 0; p < 4; ++p)
#pragma unroll
    for (int nt = 0; nt < 3; ++nt)
      bpre[p][nt] = *(const bf16x8*)(wrow[nt] + p * 32);

  // ---- P = relu(x*Wf + bf) -> sA (rows >=40 zero), octet' = octet ^ (row&7) ----
#pragma unroll
  for (int it = 0; it < 12; ++it) {
    int c = tid + it * 256;
    int s = c / 384, rem = c - s * 384;
    int r = rem >> 3, kcp = rem & 7;
    int kc = kcp ^ (r & 7);
    int k = s * 64 + kc * 8;
    bf16x8 pv;
    if (r < 40) {
      int bl = r / 10, f = r - bl * 10;
      float xv = x[(b0 + bl) * 10 + f];
      const float* wf = Wf + f * 512 + k;
      const float* bp = bfv + f * 512 + k;
#pragma unroll
      for (int j = 0; j < 8; ++j) pv[j] = (bf16)fmaxf(xv * wf[j] + bp[j], 0.f);
    } else {
#pragma unroll
      for (int j = 0; j < 8; ++j) pv[j] = (bf16)0.f;
    }
    *(bf16x8*)(sA + s * 6144 + r * 128 + kcp * 16) = pv;
  }
  __syncthreads();

  for (int h = 0; h < 8; ++h) {
    const size_t hb = (size_t)h * 98304;   // h*192*512 elems
    f32x4 acc[3][3];
#pragma unroll
    for (int i = 0; i < 3; ++i)
#pragma unroll
      for (int j = 0; j < 3; ++j) { f32x4 z = {0.f, 0.f, 0.f, 0.f}; acc[i][j] = z; }

    // ---- barrier-free K-loop: 16 chunks of K=32 ----
#pragma unroll
    for (int t = 0; t < 16; ++t) {
      if (t <= 12) wait_vm<9>();
      else if (t == 13) wait_vm<6>();
      else if (t == 14) wait_vm<3>();
      else wait_vm<0>();
      const char* sAs = sA + (t >> 1) * 6144;
      const int kc = (t & 1) * 4 + lg;
      bf16x8 af[3];
#pragma unroll
      for (int mt = 0; mt < 3; ++mt) {
        int m = mt * 16 + lm;
        af[mt] = *(const bf16x8*)(sAs + m * 128 + ((kc ^ (m & 7)) << 4));
      }
#pragma unroll
      for (int mt = 0; mt < 3; ++mt)
#pragma unroll
        for (int nt = 0; nt < 3; ++nt)
          acc[mt][nt] = __builtin_amdgcn_mfma_f32_16x16x32_bf16(af[mt], bpre[t & 3][nt], acc[mt][nt], 0, 0, 0);
      if (t < 12) {     // refill freed slot with set t+4
#pragma unroll
        for (int nt = 0; nt < 3; ++nt)
          bpre[t & 3][nt] = *(const bf16x8*)(wrow[nt] + hb + (t + 4) * 32);
      }
    }

    // cross-head prefetch: next head's sets 0..3 fly through the attention phase
    if (h < 7) {
#pragma unroll
      for (int p = 0; p < 4; ++p)
#pragma unroll
        for (int nt = 0; nt < 3; ++nt)
          bpre[p][nt] = *(const bf16x8*)(wrow[nt] + hb + 98304 + p * 32);
    }

    // ---- spill q/k/v (+bias) to shared qkv ----
#pragma unroll
    for (int nt = 0; nt < 3; ++nt) {
      int col = wave * 48 + nt * 16 + lm;
      float bias;
      if (col < 64) bias = bq[h * 64 + col];
      else if (col < 128) bias = bk[h * 64 + col - 64];
      else bias = bv[h * 64 + col - 128];
#pragma unroll
      for (int mt = 0; mt < 3; ++mt)
#pragma unroll
        for (int r = 0; r < 4; ++r) {
          int row = mt * 16 + lg * 4 + r;
          if (row < 40) qkv[row * 200 + col] = (bf16)(acc[mt][nt][r] + bias);
        }
    }
    __syncthreads();

    // ---- scores: one wave per batch elem ----
    {
      int b = wave;
#pragma unroll
      for (int pp = 0; pp < 2; ++pp) {
        int p = lane + pp * 64;
        if (p < 100) {
          int i = p / 10, j = p - i * 10;
          const bf16x8* qr = (const bf16x8*)(qkv + (b * 10 + i) * 200);
          const bf16x8* kr = (const bf16x8*)(qkv + (b * 10 + j) * 200 + 64);
          float d = 0.f;
#pragma unroll
          for (int c8 = 0; c8 < 8; ++c8) {
            bf16x8 qv = qr[c8], kv = kr[c8];
#pragma unroll
            for (int e = 0; e < 8; ++e) d += (float)qv[e] * (float)kv[e];
          }
          sc[(b * 10 + i) * 12 + j] = d * 0.125f;
        }
      }
    }
    __syncthreads();

    // ---- softmax, one thread per (b,i) ----
    if (tid < 40) {
      float* row = sc + tid * 12;
      float m = row[0];
#pragma unroll
      for (int j = 1; j < 10; ++j) m = fmaxf(m, row[j]);
      float e[10], sum = 0.f;
#pragma unroll
      for (int j = 0; j < 10; ++j) { e[j] = __expf(row[j] - m); sum += e[j]; }
      float inv = 1.f / sum;
#pragma unroll
      for (int j = 0; j < 10; ++j) row[j] = e[j] * inv;
    }
    __syncthreads();

    // ---- o = attn @ v -> O bf16 ----
#pragma unroll
    for (int u = 0; u < 10; ++u) {
      int id = tid + u * 256;
      int b = id / 640, rem2 = id - b * 640;
      int i = rem2 >> 6, d = rem2 & 63;
      const float* ar = sc + (b * 10 + i) * 12;
      float o = 0.f;
#pragma unroll
      for (int j = 0; j < 10; ++j)
        o += ar[j] * (float)qkv[(b * 10 + j) * 200 + 128 + d];
      O[((size_t)(b0 + b) * 10 + i) * 512 + h * 64 + d] = (bf16)o;
    }
    __syncthreads();   // qkv/sc dead before next head's spill
  }
}

// ---------------- O @ Wo.T + bo -> LayerNorm -> sum over F ----------------
// A and B both direct global->reg, triple-buffered sets of 11 (3A+8B), no GEMM LDS.
// LDS only for LN: lnb[48][520]bf16 | partial[48][4][2] | stats[48][2] = 51840 B.
__global__ __launch_bounds__(256, 2) void kern_out(
    const bf16* __restrict__ Oin, const bf16* __restrict__ wob,
    const float* __restrict__ bo, const float* __restrict__ gamma,
    const float* __restrict__ beta, float* __restrict__ out) {
  __shared__ __align__(16) char smem[51840];
  bf16* lnb = (bf16*)smem;                       // [48][520]
  float* partial = (float*)(smem + 49920);       // [48][4][2]
  float* stats = (float*)(smem + 51456);         // [48][2]

  const int tid = threadIdx.x;
  const int wave = tid >> 6, lane = tid & 63;
  const int lm = lane & 15, lg = lane >> 4;
  const int m0 = blockIdx.x * 40;

  const bf16* arow[3];
#pragma unroll
  for (int mt = 0; mt < 3; ++mt) {
    int r = mt * 16 + lm; if (r > 39) r = 39;
    arow[mt] = Oin + (size_t)(m0 + r) * 512 + lg * 8;
  }
  const bf16* brow[8];
#pragma unroll
  for (int nt = 0; nt < 8; ++nt)
    brow[nt] = wob + (size_t)(wave * 128 + nt * 16 + lm) * 512 + lg * 8;

  f32x4 acc[3][8];
#pragma unroll
  for (int i = 0; i < 3; ++i)
#pragma unroll
    for (int j = 0; j < 8; ++j) { f32x4 z = {0.f, 0.f, 0.f, 0.f}; acc[i][j] = z; }

  bf16x8 ap[3][3], bp[3][8];
  // prologue: sets 0..2 (33 loads)
#pragma unroll
  for (int p = 0; p < 3; ++p) {
#pragma unroll
    for (int mt = 0; mt < 3; ++mt) ap[p][mt] = *(const bf16x8*)(arow[mt] + p * 32);
#pragma unroll
    for (int nt = 0; nt < 8; ++nt) bp[p][nt] = *(const bf16x8*)(brow[nt] + p * 32);
  }

#pragma unroll
  for (int t = 0; t < 16; ++t) {
    if (t <= 13) wait_vm<22>();
    else if (t == 14) wait_vm<11>();
    else wait_vm<0>();
#pragma unroll
    for (int mt = 0; mt < 3; ++mt)
#pragma unroll
      for (int nt = 0; nt < 8; ++nt)
        acc[mt][nt] = __builtin_amdgcn_mfma_f32_16x16x32_bf16(ap[t % 3][mt], bp[t % 3][nt], acc[mt][nt], 0, 0, 0);
    if (t < 13) {      // refill freed slot with set t+3
#pragma unroll
      for (int mt = 0; mt < 3; ++mt) ap[t % 3][mt] = *(const bf16x8*)(arow[mt] + (t + 3) * 32);
#pragma unroll
      for (int nt = 0; nt < 8; ++nt) bp[t % 3][nt] = *(const bf16x8*)(brow[nt] + (t + 3) * 32);
    }
  }

  // + bias
#pragma unroll
  for (int nt = 0; nt < 8; ++nt) {
    int col = wave * 128 + nt * 16 + lm;
    float bb = bo[col];
#pragma unroll
    for (int mt = 0; mt < 3; ++mt)
#pragma unroll
      for (int r = 0; r < 4; ++r) acc[mt][nt][r] += bb;
  }

  // per-row mean/var partials
#pragma unroll
  for (int mt = 0; mt < 3; ++mt)
#pragma unroll
    for (int r = 0; r < 4; ++r) {
      float s1 = 0.f, s2 = 0.f;
#pragma unroll
      for (int nt = 0; nt < 8; ++nt) { float v = acc[mt][nt][r]; s1 += v; s2 += v * v; }
#pragma unroll
      for (int off = 1; off < 16; off <<= 1) {
        s1 += __shfl_xor(s1, off);
        s2 += __shfl_xor(s2, off);
      }
      if (lm == 0) {
        int row = mt * 16 + lg * 4 + r;
        partial[row * 8 + wave * 2 + 0] = s1;
        partial[row * 8 + wave * 2 + 1] = s2;
      }
    }
  __syncthreads();
  if (tid < 48) {
    float s1 = partial[tid * 8 + 0] + partial[tid * 8 + 2] + partial[tid * 8 + 4] + partial[tid * 8 + 6];
    float s2 = partial[tid * 8 + 1] + partial[tid * 8 + 3] + partial[tid * 8 + 5] + partial[tid * 8 + 7];
    float mu = s1 * (1.f / 512.f);
    float var = s2 * (1.f / 512.f) - mu * mu;
    stats[tid * 2 + 0] = mu;
    stats[tid * 2 + 1] = rsqrtf(var + EPS);
  }
  __syncthreads();
#pragma unroll
  for (int mt = 0; mt < 3; ++mt)
#pragma unroll
    for (int r = 0; r < 4; ++r) {
      int row = mt * 16 + lg * 4 + r;
      float mu = stats[row * 2 + 0], rr = stats[row * 2 + 1];
#pragma unroll
      for (int nt = 0; nt < 8; ++nt) {
        int col = wave * 128 + nt * 16 + lm;
        lnb[row * 520 + col] = (bf16)((acc[mt][nt][r] - mu) * rr);
      }
    }
  __syncthreads();
#pragma unroll
  for (int u = 0; u < 8; ++u) {
    int id = tid + u * 256;
    int b = id >> 9, n = id & 511;
    float ssum = 0.f;
#pragma unroll
    for (int f = 0; f < 10; ++f) ssum += (float)lnb[(b * 10 + f) * 520 + n];
    out[(size_t)(blockIdx.x * 4 + b) * 512 + n] = gamma[n] * ssum + 10.f * beta[n];
  }
}

extern "C" void kernel_launch(void* const* d_in, const int* in_sizes, int n_in,
                              void* d_out, int out_size, void* d_ws, size_t ws_size,
                              hipStream_t stream) {
  const float* x     = (const float*)d_in[0];
  const float* Wf    = (const float*)d_in[1];
  const float* bfv   = (const float*)d_in[2];
  const float* Wq    = (const float*)d_in[3];
  const float* Wk    = (const float*)d_in[4];
  const float* Wv    = (const float*)d_in[5];
  const float* bq    = (const float*)d_in[6];
  const float* bk    = (const float*)d_in[7];
  const float* bv    = (const float*)d_in[8];
  const float* Wo    = (const float*)d_in[9];
  const float* bo    = (const float*)d_in[10];
  const float* gamma = (const float*)d_in[11];
  const float* beta  = (const float*)d_in[12];
  float* out = (float*)d_out;

  char* ws = (char*)d_ws;
  bf16* O    = (bf16*)ws;
  bf16* wqkv = (bf16*)(ws + O_BYTES);
  bf16* wob  = (bf16*)(ws + O_BYTES + WQKV_BYTES);

  pack_weights<<<1024, 256, 0, stream>>>(Wq, Wk, Wv, Wo, wqkv, wob);
  kern_attn<<<4096, 256, 0, stream>>>(x, Wf, bfv, wqkv, bq, bk, bv, O);
  kern_out<<<4096, 256, 0, stream>>>(O, wob, bo, gamma, beta, out);
}

// Round 6
// 886.994 us; speedup vs baseline: 1.4517x; 1.4090x over previous
//
#include <hip/hip_runtime.h>
#include <stdint.h>

// ParallelFcWithAttention: B=16384, F=10, D=512, H=8, DH=64
// R6 = R1 (best known) with ONLY the attention phase replaced:
//  - qkv spilled WAVE-LOCAL per batch (wave w owns batch w): q/k XOR-swizzled rows,
//    q pre-scaled by 1/8, v row-major.
//  - scores = Q@K^T via 2 MFMAs (4 conflict-free ds_read_b128) instead of 32
//    divergent 1-KB ds_read_b128.
//  - softmax fully in-register (masked 16-lane xor-shuffle reductions).
//  - PV scalar with v preloaded to 10 regs + attn read as same-address LDS
//    broadcasts (free) -> 100 FMAs.
//  - barriers/head: 5 -> 3. K-loop and kern_out are R1 verbatim.
// MFMA frag (m89-verified): A/B lane holds [row=lane&15][k=(lane>>4)*8+j];
//  C/D: row=(lane>>4)*4+r, col=lane&15.

typedef __bf16 bf16;
typedef __bf16 bf16x8 __attribute__((ext_vector_type(8)));
typedef float f32x4 __attribute__((ext_vector_type(4)));

#define EPS 1e-5f

static constexpr size_t O_ELEMS   = (size_t)16384 * 10 * 512;
static constexpr size_t O_BYTES   = O_ELEMS * 2;                // 167,772,160
static constexpr size_t WQKV_BYTES = (size_t)8 * 192 * 512 * 2;

__device__ __forceinline__ void async_copy16(void* lds, const void* g) {
  __builtin_amdgcn_global_load_lds(
      (const __attribute__((address_space(1))) uint32_t*)g,
      (__attribute__((address_space(3))) uint32_t*)lds, 16, 0, 0);
}
// lgkmcnt(0) only: vmcnt=63 (bits[3:0]=0xF,[15:14]=0x3), expcnt=7, lgkm=0
__device__ __forceinline__ void wait_lgkm0() { __builtin_amdgcn_s_waitcnt(0xC07F); }

// ---------------- pack weights to bf16 ----------------
__global__ __launch_bounds__(256) void pack_weights(
    const float* __restrict__ Wq, const float* __restrict__ Wk,
    const float* __restrict__ Wv, const float* __restrict__ Wo,
    bf16* __restrict__ wqkv, bf16* __restrict__ wob) {
  int idx = blockIdx.x * 256 + threadIdx.x;
#pragma unroll
  for (int u = 0; u < 4; ++u) {
    int i = idx + u * 262144;
    if (i < 786432) {
      int pr = i >> 9, k = i & 511;
      int h = pr / 192, w = pr - h * 192;
      int t = w >> 6, r = w & 63;
      const float* src = (t == 0) ? Wq : ((t == 1) ? Wk : Wv);
      wqkv[i] = (bf16)src[(h * 64 + r) * 512 + k];
    } else {
      int j = i - 786432;
      wob[j] = (bf16)Wo[j];
    }
  }
}

// ---------------- fused P + QKV + attention ----------------
// LDS: sA = P [8 slabs(K=64)][48 rows][128B] XOR-swizzled.
//      sB 24576: GEMM: staged B slab [24 rowblocks][1024B] (R1 layout).
//        attn: per-wave 6144B region: q[16][128B]@0 (swizzled, x1/8) |
//              k[16][128B]@2048 (swizzled) | v[10][128B]@4096 | attn f32[100]@5376.
__global__ __launch_bounds__(256, 2) void kern_attn(
    const float* __restrict__ x, const float* __restrict__ Wf,
    const float* __restrict__ bfv, const bf16* __restrict__ wqkv,
    const float* __restrict__ bq, const float* __restrict__ bk,
    const float* __restrict__ bv, bf16* __restrict__ O) {
  __shared__ __align__(16) char sA[49152];
  __shared__ __align__(16) char sB[24576];

  const int tid = threadIdx.x;
  const int wave = tid >> 6, lane = tid & 63;
  const int lm = lane & 15, lg = lane >> 4;
  const int b0 = blockIdx.x * 4;

  // ---- P = relu(x*Wf + bf) into sA (rows >=40 zeroed), octet' = octet ^ (row&7) ----
#pragma unroll
  for (int it = 0; it < 12; ++it) {
    int c = tid + it * 256;
    int s = c / 384, rem = c - s * 384;
    int r = rem >> 3, kcp = rem & 7;
    int kc = kcp ^ (r & 7);
    int k = s * 64 + kc * 8;
    bf16x8 pv;
    if (r < 40) {
      int bl = r / 10, f = r - bl * 10;
      float xv = x[(b0 + bl) * 10 + f];
      const float* wf = Wf + f * 512 + k;
      const float* bp = bfv + f * 512 + k;
#pragma unroll
      for (int j = 0; j < 8; ++j) pv[j] = (bf16)fmaxf(xv * wf[j] + bp[j], 0.f);
    } else {
#pragma unroll
      for (int j = 0; j < 8; ++j) pv[j] = (bf16)0.f;
    }
    *(bf16x8*)(sA + s * 6144 + r * 128 + kcp * 16) = pv;
  }
  __syncthreads();

  const int lr = lane >> 3;
  const int kcp2 = lane & 7;
  const int kcg = kcp2 ^ lr;           // swizzled global octet for staging
  char* wbase = sB + wave * 6144;      // this wave's attention region (batch = wave)

  for (int h = 0; h < 8; ++h) {
    f32x4 acc[3][3];
#pragma unroll
    for (int i = 0; i < 3; ++i)
#pragma unroll
      for (int j = 0; j < 3; ++j) { f32x4 z = {0.f, 0.f, 0.f, 0.f}; acc[i][j] = z; }

    const bf16* wh = wqkv + (size_t)h * 98304;

    // ---- K-loop (R1 verbatim): 8 slabs of K=64, shared staged B slab ----
    for (int s = 0; s < 8; ++s) {
#pragma unroll
      for (int jb = 0; jb < 6; ++jb) {
        int rb = wave + 4 * jb;
        int rr = rb * 8 + lr;
        async_copy16(sB + rb * 1024, wh + (size_t)rr * 512 + s * 64 + kcg * 8);
      }
      __syncthreads();
#pragma unroll
      for (int kk = 0; kk < 2; ++kk) {
        int kcl = kk * 4 + lg;
        bf16x8 af[3], bfr[3];
#pragma unroll
        for (int mt = 0; mt < 3; ++mt) {
          int m = mt * 16 + lm;
          af[mt] = *(const bf16x8*)(sA + s * 6144 + m * 128 + ((kcl ^ (m & 7)) << 4));
        }
#pragma unroll
        for (int nt = 0; nt < 3; ++nt) {
          int n = wave * 48 + nt * 16 + lm;
          bfr[nt] = *(const bf16x8*)(sB + n * 128 + ((kcl ^ (n & 7)) << 4));
        }
#pragma unroll
        for (int mt = 0; mt < 3; ++mt)
#pragma unroll
          for (int nt = 0; nt < 3; ++nt)
            acc[mt][nt] = __builtin_amdgcn_mfma_f32_16x16x32_bf16(af[mt], bfr[nt], acc[mt][nt], 0, 0, 0);
      }
      __syncthreads();
    }

    // ---- spill q/k/v (+bias) WAVE-LOCAL per batch; q scaled 1/8, q/k swizzled ----
#pragma unroll
    for (int nt = 0; nt < 3; ++nt) {
      int col = wave * 48 + nt * 16 + lm;
      float bias;
      if (col < 64) bias = bq[h * 64 + col];
      else if (col < 128) bias = bk[h * 64 + col - 64];
      else bias = bv[h * 64 + col - 128];
#pragma unroll
      for (int mt = 0; mt < 3; ++mt)
#pragma unroll
        for (int r = 0; r < 4; ++r) {
          int row = mt * 16 + lg * 4 + r;
          if (row < 40) {
            int b = row / 10, i = row - b * 10;
            char* tb = sB + b * 6144;
            float v = acc[mt][nt][r] + bias;
            if (col < 64) {
              int c = col, oct = c >> 3;
              *(bf16*)(tb + i * 128 + ((oct ^ (i & 7)) << 4) + (c & 7) * 2) = (bf16)(v * 0.125f);
            } else if (col < 128) {
              int c = col - 64, oct = c >> 3;
              *(bf16*)(tb + 2048 + i * 128 + ((oct ^ (i & 7)) << 4) + (c & 7) * 2) = (bf16)v;
            } else {
              int c = col - 128;
              *(bf16*)(tb + 4096 + i * 128 + c * 2) = (bf16)v;
            }
          }
        }
    }
    __syncthreads();

    // ---- wave-local attention for batch b = wave ----
    // scores S = (q/8) @ k^T : M=16(10),N=16(10),K=64 -> 2 MFMAs
    f32x4 s4 = {0.f, 0.f, 0.f, 0.f};
#pragma unroll
    for (int kk = 0; kk < 2; ++kk) {
      int oct = kk * 4 + lg;
      bf16x8 qf = *(const bf16x8*)(wbase + lm * 128 + ((oct ^ (lm & 7)) << 4));
      bf16x8 kf = *(const bf16x8*)(wbase + 2048 + lm * 128 + ((oct ^ (lm & 7)) << 4));
      s4 = __builtin_amdgcn_mfma_f32_16x16x32_bf16(qf, kf, s4, 0, 0, 0);
    }
    // masked softmax in-register; write normalized weights to attn LDS (f32[100])
    float* aL = (float*)(wbase + 5376);
#pragma unroll
    for (int r = 0; r < 4; ++r) {
      int i = lg * 4 + r;
      float val = s4[r];
      float m = (lm < 10) ? val : -3.0e38f;
#pragma unroll
      for (int off = 1; off < 16; off <<= 1) m = fmaxf(m, __shfl_xor(m, off));
      float e = (lm < 10) ? __expf(val - m) : 0.f;
      float sum = e;
#pragma unroll
      for (int off = 1; off < 16; off <<= 1) sum += __shfl_xor(sum, off);
      if (i < 10 && lm < 10) aL[i * 10 + lm] = e / sum;
    }
    wait_lgkm0();   // wave-local LDS write->read ordering (no barrier needed)

    // PV: v preloaded to regs (lane = d), attn via same-address broadcast reads
    float vj[10];
#pragma unroll
    for (int j = 0; j < 10; ++j)
      vj[j] = (float)*(const bf16*)(wbase + 4096 + j * 128 + lane * 2);
    const size_t obase = ((size_t)(b0 + wave) * 10) * 512 + (size_t)h * 64 + lane;
#pragma unroll
    for (int i = 0; i < 10; ++i) {
      float o = 0.f;
#pragma unroll
      for (int j = 0; j < 10; ++j) o += aL[i * 10 + j] * vj[j];
      O[obase + (size_t)i * 512] = (bf16)o;
    }
    __syncthreads();   // attn region dead before next head's staging
  }
}

// ---------------- O @ Wo.T + bo -> LayerNorm -> sum over F (R1 verbatim) ----------------
__global__ __launch_bounds__(256, 2) void kern_out(
    const bf16* __restrict__ O, const bf16* __restrict__ wob,
    const float* __restrict__ bo, const float* __restrict__ gamma,
    const float* __restrict__ beta, float* __restrict__ out) {
  __shared__ __align__(16) char sAB[71680];
  __shared__ float partial[48][4][2];
  __shared__ float stats[48][2];
  char* As = sAB;
  char* Bs = sAB + 6144;
  bf16* lnb = (bf16*)sAB;

  const int tid = threadIdx.x;
  const int wave = tid >> 6, lane = tid & 63;
  const int lm = lane & 15, lg = lane >> 4;
  const int m0 = blockIdx.x * 40;

  f32x4 acc[3][8];
#pragma unroll
  for (int i = 0; i < 3; ++i)
#pragma unroll
    for (int j = 0; j < 8; ++j) { f32x4 z = {0.f, 0.f, 0.f, 0.f}; acc[i][j] = z; }

  const int lr = lane >> 3;
  const int kcp2 = lane & 7;
  const int kcg = kcp2 ^ lr;

  for (int s = 0; s < 8; ++s) {
    {
      int rr = wave * 8 + lr;
      int rm = min(rr, 39);
      async_copy16(As + wave * 1024, O + (size_t)(m0 + rm) * 512 + s * 64 + kcg * 8);
      if (wave < 2) {
        int rr2 = (4 + wave) * 8 + lr;
        int rm2 = min(rr2, 39);
        async_copy16(As + (4 + wave) * 1024, O + (size_t)(m0 + rm2) * 512 + s * 64 + kcg * 8);
      }
    }
#pragma unroll
    for (int jb = 0; jb < 16; ++jb) {
      int rb = wave + 4 * jb;
      int n = rb * 8 + lr;
      async_copy16(Bs + rb * 1024, wob + (size_t)n * 512 + s * 64 + kcg * 8);
    }
    __syncthreads();
#pragma unroll
    for (int kk = 0; kk < 2; ++kk) {
      int kcl = kk * 4 + lg;
      bf16x8 af[3], bfr[8];
#pragma unroll
      for (int mt = 0; mt < 3; ++mt) {
        int m = mt * 16 + lm;
        af[mt] = *(const bf16x8*)(As + m * 128 + ((kcl ^ (m & 7)) << 4));
      }
#pragma unroll
      for (int nt = 0; nt < 8; ++nt) {
        int n = wave * 128 + nt * 16 + lm;
        bfr[nt] = *(const bf16x8*)(Bs + n * 128 + ((kcl ^ (n & 7)) << 4));
      }
#pragma unroll
      for (int mt = 0; mt < 3; ++mt)
#pragma unroll
        for (int nt = 0; nt < 8; ++nt)
          acc[mt][nt] = __builtin_amdgcn_mfma_f32_16x16x32_bf16(af[mt], bfr[nt], acc[mt][nt], 0, 0, 0);
    }
    __syncthreads();
  }

#pragma unroll
  for (int nt = 0; nt < 8; ++nt) {
    int col = wave * 128 + nt * 16 + lm;
    float bb = bo[col];
#pragma unroll
    for (int mt = 0; mt < 3; ++mt)
#pragma unroll
      for (int r = 0; r < 4; ++r) acc[mt][nt][r] += bb;
  }

#pragma unroll
  for (int mt = 0; mt < 3; ++mt)
#pragma unroll
    for (int r = 0; r < 4; ++r) {
      float s1 = 0.f, s2 = 0.f;
#pragma unroll
      for (int nt = 0; nt < 8; ++nt) { float v = acc[mt][nt][r]; s1 += v; s2 += v * v; }
#pragma unroll
      for (int off = 1; off < 16; off <<= 1) {
        s1 += __shfl_xor(s1, off);
        s2 += __shfl_xor(s2, off);
      }
      if (lm == 0) {
        int row = mt * 16 + lg * 4 + r;
        partial[row][wave][0] = s1;
        partial[row][wave][1] = s2;
      }
    }
  __syncthreads();
  if (tid < 48) {
    float s1 = partial[tid][0][0] + partial[tid][1][0] + partial[tid][2][0] + partial[tid][3][0];
    float s2 = partial[tid][0][1] + partial[tid][1][1] + partial[tid][2][1] + partial[tid][3][1];
    float mu = s1 * (1.f / 512.f);
    float var = s2 * (1.f / 512.f) - mu * mu;
    stats[tid][0] = mu;
    stats[tid][1] = rsqrtf(var + EPS);
  }
  __syncthreads();
#pragma unroll
  for (int mt = 0; mt < 3; ++mt)
#pragma unroll
    for (int r = 0; r < 4; ++r) {
      int row = mt * 16 + lg * 4 + r;
      float mu = stats[row][0], rr = stats[row][1];
#pragma unroll
      for (int nt = 0; nt < 8; ++nt) {
        int col = wave * 128 + nt * 16 + lm;
        lnb[row * 520 + col] = (bf16)((acc[mt][nt][r] - mu) * rr);
      }
    }
  __syncthreads();
#pragma unroll
  for (int u = 0; u < 8; ++u) {
    int id = tid + u * 256;
    int b = id >> 9, n = id & 511;
    float ssum = 0.f;
#pragma unroll
    for (int f = 0; f < 10; ++f) ssum += (float)lnb[(b * 10 + f) * 520 + n];
    out[(size_t)(blockIdx.x * 4 + b) * 512 + n] = gamma[n] * ssum + 10.f * beta[n];
  }
}

extern "C" void kernel_launch(void* const* d_in, const int* in_sizes, int n_in,
                              void* d_out, int out_size, void* d_ws, size_t ws_size,
                              hipStream_t stream) {
  const float* x     = (const float*)d_in[0];
  const float* Wf    = (const float*)d_in[1];
  const float* bfv   = (const float*)d_in[2];
  const float* Wq    = (const float*)d_in[3];
  const float* Wk    = (const float*)d_in[4];
  const float* Wv    = (const float*)d_in[5];
  const float* bq    = (const float*)d_in[6];
  const float* bk    = (const float*)d_in[7];
  const float* bv    = (const float*)d_in[8];
  const float* Wo    = (const float*)d_in[9];
  const float* bo    = (const float*)d_in[10];
  const float* gamma = (const float*)d_in[11];
  const float* beta  = (const float*)d_in[12];
  float* out = (float*)d_out;

  char* ws = (char*)d_ws;
  bf16* O    = (bf16*)ws;
  bf16* wqkv = (bf16*)(ws + O_BYTES);
  bf16* wob  = (bf16*)(ws + O_BYTES + WQKV_BYTES);

  pack_weights<<<1024, 256, 0, stream>>>(Wq, Wk, Wv, Wo, wqkv, wob);
  kern_attn<<<4096, 256, 0, stream>>>(x, Wf, bfv, wqkv, bq, bk, bv, O);
  kern_out<<<4096, 256, 0, stream>>>(O, wob, bo, gamma, beta, out);
}